// Round 3
// baseline (2994.380 us; speedup 1.0000x reference)
//
#include <hip/hip_runtime.h>
#include <math.h>

// Dims (fixed by the problem)
#define B_  256
#define T_  64
#define D_  6400
#define H_  1000
#define A_  4

#define BM 256
#define BN 128
#define BK 16

typedef float v2f __attribute__((ext_vector_type(2)));

// v_pk_fma_f32: D.lo = sel(S0)*S1.lo + S2.lo ; D.hi = sel_hi(S0)*S1.hi + S2.hi
// LO: use S0.lo for both halves; HI: use S0.hi for both halves.
#define PK_FMA_LO(acc, a, b)                                          \
  asm("v_pk_fma_f32 %0, %1, %2, %0 op_sel:[0,0,0] op_sel_hi:[0,1,1]" \
      : "+v"(acc)                                                     \
      : "v"(a), "v"(b))
#define PK_FMA_HI(acc, a, b)                                          \
  asm("v_pk_fma_f32 %0, %1, %2, %0 op_sel:[1,0,0] op_sel_hi:[1,1,1]" \
      : "+v"(acc)                                                     \
      : "v"(a), "v"(b))

// Raw barrier: drain LDS ops only (cross-wave visibility), leave prefetch
// global loads in flight across the barrier (they only feed private VGPRs;
// the compiler inserts its own vmcnt wait before the dependent ds_writes).
#define LGKM_BARRIER()                                         \
  do {                                                         \
    asm volatile("s_waitcnt lgkmcnt(0)" ::: "memory");         \
    __builtin_amdgcn_s_barrier();                              \
  } while (0)

// ---------------------------------------------------------------------------
// Kernel 1: C1[t][b][h] = x[b][t][:] . W1[h][:] + b1[h]
// Block tile 256(M) x 128(N), BK=16; thread micro-tile 16x8 via v_pk_fma_f32.
// DOUBLE-BUFFERED LDS: one lgkm-only barrier per tile (was 2 full-drain
// __syncthreads per tile). Per-element FMA order (k ascending, IEEE fma) is
// unchanged -> bitwise-identical C1 -> identical spikes.
// ---------------------------------------------------------------------------
__global__ __launch_bounds__(256, 2) void gemm1_kernel(
    const float* __restrict__ x, const float* __restrict__ W1,
    const float* __restrict__ b1, float* __restrict__ C1) {
  __shared__ float As[2][BK][BM + 4];  // [buf][k][m], stride 260
  __shared__ float Bs[2][BK][BN + 4];  // [buf][k][n], stride 132

  const int tid = threadIdx.x;
  const int m0 = blockIdx.y * BM;
  const int n0 = blockIdx.x * BN;
  const int tx = tid & 15;   // cols {tx*4..+3, 64+tx*4..+3}
  const int ty = tid >> 4;   // rows {ty*4..+3, +64, +128, +192}

  const int row = tid >> 2;  // 0..63 staging row within 64-row chunk
  const int col4 = tid & 3;  // float4 column 0..3 (BK=16)

  v2f acc2[16][4];
#pragma unroll
  for (int i = 0; i < 16; ++i)
#pragma unroll
    for (int j = 0; j < 4; ++j) acc2[i][j] = (v2f){0.f, 0.f};

  float4 av[4], bv[2];

#define LOAD_TILE(kn)                                                         \
  do {                                                                        \
    if ((kn) < D_) {                                                          \
      _Pragma("unroll") for (int i = 0; i < 4; ++i) av[i] =                   \
          *(const float4*)(x + (size_t)(m0 + row + 64 * i) * D_ + (kn) +     \
                           col4 * 4);                                         \
      _Pragma("unroll") for (int i = 0; i < 2; ++i) {                         \
        const int hh = n0 + row + 64 * i;                                     \
        bv[i] = (hh < H_)                                                     \
                    ? *(const float4*)(W1 + (size_t)hh * D_ + (kn) +         \
                                       col4 * 4)                              \
                    : make_float4(0.f, 0.f, 0.f, 0.f);                        \
      }                                                                       \
    }                                                                         \
  } while (0)

#define STORE_TILE(bufi)                                                      \
  do {                                                                        \
    _Pragma("unroll") for (int i = 0; i < 4; ++i) {                           \
      const int r = row + 64 * i;                                             \
      As[bufi][col4 * 4 + 0][r] = av[i].x;                                    \
      As[bufi][col4 * 4 + 1][r] = av[i].y;                                    \
      As[bufi][col4 * 4 + 2][r] = av[i].z;                                    \
      As[bufi][col4 * 4 + 3][r] = av[i].w;                                    \
    }                                                                         \
    _Pragma("unroll") for (int i = 0; i < 2; ++i) {                           \
      const int r = row + 64 * i;                                             \
      Bs[bufi][col4 * 4 + 0][r] = bv[i].x;                                    \
      Bs[bufi][col4 * 4 + 1][r] = bv[i].y;                                    \
      Bs[bufi][col4 * 4 + 2][r] = bv[i].z;                                    \
      Bs[bufi][col4 * 4 + 3][r] = bv[i].w;                                    \
    }                                                                         \
  } while (0)

  // ---- prologue: tile 0 -> buf0; tile 1 -> regs ----
  LOAD_TILE(0);
  STORE_TILE(0);
  LOAD_TILE(BK);
  LGKM_BARRIER();

  int cur = 0;
  for (int k0 = 0; k0 < D_; k0 += BK) {
    const int nxt = cur ^ 1;
    // ---- stage next tile (regs->LDS other buffer), issue tile+2 loads ----
    if (k0 + BK < D_) {
      STORE_TILE(nxt);
      LOAD_TILE(k0 + 2 * BK);
    }
    // ---- compute: 16 k-steps x 64 pk-FMA from buf[cur] ----
#pragma unroll
    for (int k = 0; k < BK; ++k) {
      const float4 a0 = *(const float4*)&As[cur][k][ty * 4];
      const float4 a1 = *(const float4*)&As[cur][k][64 + ty * 4];
      const float4 a2 = *(const float4*)&As[cur][k][128 + ty * 4];
      const float4 a3 = *(const float4*)&As[cur][k][192 + ty * 4];
      const float4 b0 = *(const float4*)&Bs[cur][k][tx * 4];
      const float4 b1v = *(const float4*)&Bs[cur][k][64 + tx * 4];
      v2f ap[8] = {{a0.x, a0.y}, {a0.z, a0.w}, {a1.x, a1.y}, {a1.z, a1.w},
                   {a2.x, a2.y}, {a2.z, a2.w}, {a3.x, a3.y}, {a3.z, a3.w}};
      v2f bp[4] = {{b0.x, b0.y}, {b0.z, b0.w}, {b1v.x, b1v.y}, {b1v.z, b1v.w}};
#pragma unroll
      for (int p = 0; p < 8; ++p) {
#pragma unroll
        for (int j = 0; j < 4; ++j) {
          PK_FMA_LO(acc2[2 * p][j], ap[p], bp[j]);
          PK_FMA_HI(acc2[2 * p + 1][j], ap[p], bp[j]);
        }
      }
    }
    LGKM_BARRIER();
    cur = nxt;
  }

  // ---- epilogue: +b1, scatter rows to [T][B][H] ----
  const int h0 = n0 + tx * 4;
  const int h1 = n0 + 64 + tx * 4;
  float4 bias0 = (h0 < H_) ? *(const float4*)(b1 + h0)
                           : make_float4(0.f, 0.f, 0.f, 0.f);
  float4 bias1 = (h1 < H_) ? *(const float4*)(b1 + h1)
                           : make_float4(0.f, 0.f, 0.f, 0.f);
#pragma unroll
  for (int f = 0; f < 16; ++f) {
    const int m = m0 + 64 * (f >> 2) + ty * 4 + (f & 3);
    const int bb = m >> 6;  // batch
    const int tt = m & 63;  // timestep
    float* op = C1 + (size_t)tt * (B_ * H_) + (size_t)bb * H_;
    if (h0 < H_) {
      float4 r;
      r.x = acc2[f][0].x + bias0.x;
      r.y = acc2[f][0].y + bias0.y;
      r.z = acc2[f][1].x + bias0.z;
      r.w = acc2[f][1].y + bias0.w;
      *(float4*)(op + h0) = r;
    }
    if (h1 < H_) {
      float4 r;
      r.x = acc2[f][2].x + bias1.x;
      r.y = acc2[f][2].y + bias1.y;
      r.z = acc2[f][3].x + bias1.z;
      r.w = acc2[f][3].y + bias1.w;
      *(float4*)(op + h1) = r;
    }
  }
#undef LOAD_TILE
#undef STORE_TILE
}

// ---------------------------------------------------------------------------
// Kernel 2: recurrent LIF dynamics. One block per batch element.
// float4 row layout (h = 4*tid), W2 in registers, u2 staged to LDS once,
// t+1 rows prefetched under the reduce chain, sRed double-buffered ->
// one barrier per timestep.
// ---------------------------------------------------------------------------
__device__ __forceinline__ float sigmoid_f(float z) {
  return 1.0f / (1.0f + expf(-z));
}

__global__ __launch_bounds__(256) void snn_seq_kernel(
    const float* __restrict__ C1, const float* __restrict__ u1,
    const float* __restrict__ W2, const float* __restrict__ b2,
    const float* __restrict__ u2, float* __restrict__ out) {
  const int b = blockIdx.x;
  const int tid = threadIdx.x;
  const int lane = tid & 63;
  const int wv = tid >> 6;

  __shared__ float sRed[2][4][A_];
  __shared__ float sU2[T_ * A_];  // 256 floats: u2[:, b, :]

  // stage u2 slice for this batch (one value per thread; T_*A_ == 256)
  sU2[tid] = u2[(size_t)(tid >> 2) * (B_ * A_) + (size_t)b * A_ + (tid & 3)];

  const bool act = (tid < 250);  // h = 4*tid .. 4*tid+3 < 1000
  const int h = tid * 4;

  // W2 rows for this thread's 4 h-values, held in registers (16 VGPRs)
  float wreg[A_][4];
#pragma unroll
  for (int a = 0; a < A_; ++a)
#pragma unroll
    for (int j = 0; j < 4; ++j) wreg[a][j] = 0.f;
  if (act) {
#pragma unroll
    for (int a = 0; a < A_; ++a) {
      const float4 w = *(const float4*)(W2 + (size_t)a * H_ + h);
      wreg[a][0] = w.x;
      wreg[a][1] = w.y;
      wreg[a][2] = w.z;
      wreg[a][3] = w.w;
    }
  }
  const float b2v = (tid < A_) ? b2[tid] : 0.f;

  __syncthreads();  // sU2 visible

  float mem1v[4] = {0.f, 0.f, 0.f, 0.f};
  float th1v[4] = {0.f, 0.f, 0.f, 0.f};
  float mem2v = 0.f, th2v = 0.f, scnt = 0.f;

  // prefetch t=0 rows
  float4 c_cur = make_float4(0.f, 0.f, 0.f, 0.f);
  float4 u_cur = make_float4(0.f, 0.f, 0.f, 0.f);
  if (act) {
    c_cur = *(const float4*)(C1 + (size_t)b * H_ + h);
    u_cur = *(const float4*)(u1 + (size_t)b * H_ + h);
  }

  for (int t = 0; t < T_; ++t) {
    // ---- issue t+1 loads early: latency hides under reduce+barrier ----
    float4 c_nxt = make_float4(0.f, 0.f, 0.f, 0.f);
    float4 u_nxt = make_float4(0.f, 0.f, 0.f, 0.f);
    if (act && (t + 1 < T_)) {
      const size_t off = ((size_t)(t + 1) * B_ + b) * H_ + h;
      c_nxt = *(const float4*)(C1 + off);
      u_nxt = *(const float4*)(u1 + off);
    }

    // ---- layer-1 LIF + spike-gated W2 accumulation ----
    float part0 = 0.f, part1 = 0.f, part2 = 0.f, part3 = 0.f;
    if (act) {
      const float cs[4] = {c_cur.x, c_cur.y, c_cur.z, c_cur.w};
      const float us[4] = {u_cur.x, u_cur.y, u_cur.z, u_cur.w};
#pragma unroll
      for (int j = 0; j < 4; ++j) {
        float m = fmaf(0.9f, mem1v[j], cs[j]);
        const float z = m - (1.0f + th1v[j]);
        const float p = sigmoid_f(z);
        const float spk = (us[j] < p) ? 1.0f : 0.0f;
        m = (spk != 0.0f) ? 0.0f : m;
        th1v[j] = fmaf(0.9f, th1v[j], 0.05f * spk);
        mem1v[j] = m;
        part0 = fmaf(spk, wreg[0][j], part0);
        part1 = fmaf(spk, wreg[1][j], part1);
        part2 = fmaf(spk, wreg[2][j], part2);
        part3 = fmaf(spk, wreg[3][j], part3);
      }
    }

    // ---- wave-level tree reduce (64 lanes) ----
#pragma unroll
    for (int off = 32; off >= 1; off >>= 1) {
      part0 += __shfl_down(part0, off);
      part1 += __shfl_down(part1, off);
      part2 += __shfl_down(part2, off);
      part3 += __shfl_down(part3, off);
    }
    if (lane == 0) {
      float* r = &sRed[t & 1][wv][0];
      r[0] = part0;
      r[1] = part1;
      r[2] = part2;
      r[3] = part3;
    }
    __syncthreads();

    // ---- layer-2 LIF: 4 lanes, one action each ----
    if (tid < A_) {
      const int a = tid;
      const float cur2 = sRed[t & 1][0][a] + sRed[t & 1][1][a] +
                         sRed[t & 1][2][a] + sRed[t & 1][3][a] + b2v;
      float m = fmaf(0.9f, mem2v, cur2);
      const float z = m - (1.0f + th2v);
      const float p = sigmoid_f(z);
      const float u = sU2[t * A_ + a];
      const float spk = (u < p) ? 1.0f : 0.0f;
      mem2v = (spk != 0.0f) ? 0.0f : m;
      th2v = fmaf(0.9f, th2v, 0.05f * spk);
      scnt += spk;
    }

    c_cur = c_nxt;
    u_cur = u_nxt;
  }

  if (tid < A_) out[b * A_ + tid] = scnt * (1.0f / 64.0f);
}

extern "C" void kernel_launch(void* const* d_in, const int* in_sizes, int n_in,
                              void* d_out, int out_size, void* d_ws,
                              size_t ws_size, hipStream_t stream) {
  const float* x = (const float*)d_in[0];   // [B,T,D]
  const float* W1 = (const float*)d_in[1];  // [H,D]
  const float* b1 = (const float*)d_in[2];  // [H]
  const float* W2 = (const float*)d_in[3];  // [A,H]
  const float* b2 = (const float*)d_in[4];  // [A]
  const float* u1 = (const float*)d_in[5];  // [T,B,H]
  const float* u2 = (const float*)d_in[6];  // [T,B,A]
  float* out = (float*)d_out;               // [B,A]
  float* C1 = (float*)d_ws;                 // [T,B,H] = 65.536 MB scratch

  dim3 g1((H_ + BN - 1) / BN, (B_ * T_) / BM);  // (8, 64)
  gemm1_kernel<<<g1, 256, 0, stream>>>(x, W1, b1, C1);
  snn_seq_kernel<<<B_, 256, 0, stream>>>(C1, u1, W2, b2, u2, out);
}

// Round 4
// 2959.626 us; speedup vs baseline: 1.0117x; 1.0117x over previous
//
#include <hip/hip_runtime.h>
#include <math.h>

// Dims (fixed by the problem)
#define B_  256
#define T_  64
#define D_  6400
#define H_  1000
#define A_  4

#define BM 256
#define BN 128
#define BK 16

typedef float v2f __attribute__((ext_vector_type(2)));

// Packed fp32 FMA via compiler intrinsics (NOT inline asm).
// acc.x = fma(a, b.x, acc.x); acc.y = fma(a, b.y, acc.y)
// Same IEEE fma, same k-ascending order per element as the scalar reference
// chain -> bitwise-identical C1 -> identical spikes.
// Rationale (r3 counters): the inline-asm version forced 64 tied aligned
// "+v" pairs; allocator shunted accumulators to AGPRs (VGPR_Count=104 <
// 128 live accs) and VALUBusy hit 74% with only 27% of issue slots being
// FMAs (84.6 TF of a 314 TF pk ceiling) -- ~2.7x VALU bloat from
// accvgpr/mov marshalling. Plain IR frees the allocator.
__device__ __forceinline__ void pk_fma(v2f& acc, float a, v2f b) {
  v2f as = {a, a};
  acc = __builtin_elementwise_fma(as, b, acc);
}

// Raw barrier: drain LDS ops only (cross-wave visibility), leave prefetch
// global loads in flight across the barrier (they only feed private VGPRs;
// the compiler inserts its own vmcnt wait before the dependent ds_writes).
#define LGKM_BARRIER()                                         \
  do {                                                         \
    asm volatile("s_waitcnt lgkmcnt(0)" ::: "memory");         \
    __builtin_amdgcn_s_barrier();                              \
  } while (0)

// ---------------------------------------------------------------------------
// Kernel 1: C1[t][b][h] = x[b][t][:] . W1[h][:] + b1[h]
// Block tile 256(M) x 128(N), BK=16; thread micro-tile 16x8 via v_pk_fma_f32.
// Double-buffered LDS, one lgkm-only barrier per tile.
// ---------------------------------------------------------------------------
__global__ __launch_bounds__(256, 2) void gemm1_kernel(
    const float* __restrict__ x, const float* __restrict__ W1,
    const float* __restrict__ b1, float* __restrict__ C1) {
  __shared__ float As[2][BK][BM + 4];  // [buf][k][m], stride 260
  __shared__ float Bs[2][BK][BN + 4];  // [buf][k][n], stride 132

  const int tid = threadIdx.x;
  const int m0 = blockIdx.y * BM;
  const int n0 = blockIdx.x * BN;
  const int tx = tid & 15;   // cols {tx*4..+3, 64+tx*4..+3}
  const int ty = tid >> 4;   // rows {ty*4..+3, +64, +128, +192}

  const int row = tid >> 2;  // 0..63 staging row within 64-row chunk
  const int col4 = tid & 3;  // float4 column 0..3 (BK=16)

  v2f acc2[16][4];
#pragma unroll
  for (int i = 0; i < 16; ++i)
#pragma unroll
    for (int j = 0; j < 4; ++j) acc2[i][j] = (v2f){0.f, 0.f};

  float4 av[4], bv[2];

#define LOAD_TILE(kn)                                                         \
  do {                                                                        \
    if ((kn) < D_) {                                                          \
      _Pragma("unroll") for (int i = 0; i < 4; ++i) av[i] =                   \
          *(const float4*)(x + (size_t)(m0 + row + 64 * i) * D_ + (kn) +     \
                           col4 * 4);                                         \
      _Pragma("unroll") for (int i = 0; i < 2; ++i) {                         \
        const int hh = n0 + row + 64 * i;                                     \
        bv[i] = (hh < H_)                                                     \
                    ? *(const float4*)(W1 + (size_t)hh * D_ + (kn) +         \
                                       col4 * 4)                              \
                    : make_float4(0.f, 0.f, 0.f, 0.f);                        \
      }                                                                       \
    }                                                                         \
  } while (0)

#define STORE_TILE(bufi)                                                      \
  do {                                                                        \
    _Pragma("unroll") for (int i = 0; i < 4; ++i) {                           \
      const int r = row + 64 * i;                                             \
      As[bufi][col4 * 4 + 0][r] = av[i].x;                                    \
      As[bufi][col4 * 4 + 1][r] = av[i].y;                                    \
      As[bufi][col4 * 4 + 2][r] = av[i].z;                                    \
      As[bufi][col4 * 4 + 3][r] = av[i].w;                                    \
    }                                                                         \
    _Pragma("unroll") for (int i = 0; i < 2; ++i) {                           \
      const int r = row + 64 * i;                                             \
      Bs[bufi][col4 * 4 + 0][r] = bv[i].x;                                    \
      Bs[bufi][col4 * 4 + 1][r] = bv[i].y;                                    \
      Bs[bufi][col4 * 4 + 2][r] = bv[i].z;                                    \
      Bs[bufi][col4 * 4 + 3][r] = bv[i].w;                                    \
    }                                                                         \
  } while (0)

  // ---- prologue: tile 0 -> buf0; tile 1 -> regs ----
  LOAD_TILE(0);
  STORE_TILE(0);
  LOAD_TILE(BK);
  LGKM_BARRIER();

  int cur = 0;
  for (int k0 = 0; k0 < D_; k0 += BK) {
    const int nxt = cur ^ 1;
    // ---- stage next tile (regs->LDS other buffer), issue tile+2 loads ----
    if (k0 + BK < D_) {
      STORE_TILE(nxt);
      LOAD_TILE(k0 + 2 * BK);
    }
    // ---- compute: 16 k-steps x 64 pk-FMA from buf[cur] ----
#pragma unroll
    for (int k = 0; k < BK; ++k) {
      const float4 a0 = *(const float4*)&As[cur][k][ty * 4];
      const float4 a1 = *(const float4*)&As[cur][k][64 + ty * 4];
      const float4 a2 = *(const float4*)&As[cur][k][128 + ty * 4];
      const float4 a3 = *(const float4*)&As[cur][k][192 + ty * 4];
      const float4 b0 = *(const float4*)&Bs[cur][k][tx * 4];
      const float4 b1v = *(const float4*)&Bs[cur][k][64 + tx * 4];
      v2f bp[4] = {{b0.x, b0.y}, {b0.z, b0.w}, {b1v.x, b1v.y}, {b1v.z, b1v.w}};
      const float as_[16] = {a0.x, a0.y, a0.z, a0.w, a1.x, a1.y, a1.z, a1.w,
                             a2.x, a2.y, a2.z, a2.w, a3.x, a3.y, a3.z, a3.w};
#pragma unroll
      for (int f = 0; f < 16; ++f) {
#pragma unroll
        for (int j = 0; j < 4; ++j) {
          pk_fma(acc2[f][j], as_[f], bp[j]);
        }
      }
    }
    LGKM_BARRIER();
    cur = nxt;
  }

  // ---- epilogue: +b1, scatter rows to [T][B][H] ----
  // acc2[f] -> row m0 + 64*(f>>2) + ty*4 + (f&3)
  // cols: acc2[f][0..1] -> h0+0..3 ; acc2[f][2..3] -> h1+0..3
  const int h0 = n0 + tx * 4;
  const int h1 = n0 + 64 + tx * 4;
  float4 bias0 = (h0 < H_) ? *(const float4*)(b1 + h0)
                           : make_float4(0.f, 0.f, 0.f, 0.f);
  float4 bias1 = (h1 < H_) ? *(const float4*)(b1 + h1)
                           : make_float4(0.f, 0.f, 0.f, 0.f);
#pragma unroll
  for (int f = 0; f < 16; ++f) {
    const int m = m0 + 64 * (f >> 2) + ty * 4 + (f & 3);
    const int bb = m >> 6;  // batch
    const int tt = m & 63;  // timestep
    float* op = C1 + (size_t)tt * (B_ * H_) + (size_t)bb * H_;
    if (h0 < H_) {
      float4 r;
      r.x = acc2[f][0].x + bias0.x;
      r.y = acc2[f][0].y + bias0.y;
      r.z = acc2[f][1].x + bias0.z;
      r.w = acc2[f][1].y + bias0.w;
      *(float4*)(op + h0) = r;
    }
    if (h1 < H_) {
      float4 r;
      r.x = acc2[f][2].x + bias1.x;
      r.y = acc2[f][2].y + bias1.y;
      r.z = acc2[f][3].x + bias1.z;
      r.w = acc2[f][3].y + bias1.w;
      *(float4*)(op + h1) = r;
    }
  }
#undef LOAD_TILE
#undef STORE_TILE
}

// ---------------------------------------------------------------------------
// Kernel 2: recurrent LIF dynamics. One block per batch element.
// float4 row layout (h = 4*tid), W2 in registers, u2 staged to LDS once,
// t+1 rows prefetched under the reduce chain, sRed double-buffered ->
// one barrier per timestep.
// ---------------------------------------------------------------------------
__device__ __forceinline__ float sigmoid_f(float z) {
  return 1.0f / (1.0f + expf(-z));
}

__global__ __launch_bounds__(256) void snn_seq_kernel(
    const float* __restrict__ C1, const float* __restrict__ u1,
    const float* __restrict__ W2, const float* __restrict__ b2,
    const float* __restrict__ u2, float* __restrict__ out) {
  const int b = blockIdx.x;
  const int tid = threadIdx.x;
  const int lane = tid & 63;
  const int wv = tid >> 6;

  __shared__ float sRed[2][4][A_];
  __shared__ float sU2[T_ * A_];  // 256 floats: u2[:, b, :]

  // stage u2 slice for this batch (one value per thread; T_*A_ == 256)
  sU2[tid] = u2[(size_t)(tid >> 2) * (B_ * A_) + (size_t)b * A_ + (tid & 3)];

  const bool act = (tid < 250);  // h = 4*tid .. 4*tid+3 < 1000
  const int h = tid * 4;

  // W2 rows for this thread's 4 h-values, held in registers (16 VGPRs)
  float wreg[A_][4];
#pragma unroll
  for (int a = 0; a < A_; ++a)
#pragma unroll
    for (int j = 0; j < 4; ++j) wreg[a][j] = 0.f;
  if (act) {
#pragma unroll
    for (int a = 0; a < A_; ++a) {
      const float4 w = *(const float4*)(W2 + (size_t)a * H_ + h);
      wreg[a][0] = w.x;
      wreg[a][1] = w.y;
      wreg[a][2] = w.z;
      wreg[a][3] = w.w;
    }
  }
  const float b2v = (tid < A_) ? b2[tid] : 0.f;

  __syncthreads();  // sU2 visible

  float mem1v[4] = {0.f, 0.f, 0.f, 0.f};
  float th1v[4] = {0.f, 0.f, 0.f, 0.f};
  float mem2v = 0.f, th2v = 0.f, scnt = 0.f;

  // prefetch t=0 rows
  float4 c_cur = make_float4(0.f, 0.f, 0.f, 0.f);
  float4 u_cur = make_float4(0.f, 0.f, 0.f, 0.f);
  if (act) {
    c_cur = *(const float4*)(C1 + (size_t)b * H_ + h);
    u_cur = *(const float4*)(u1 + (size_t)b * H_ + h);
  }

  for (int t = 0; t < T_; ++t) {
    // ---- issue t+1 loads early: latency hides under reduce chain ----
    float4 c_nxt = make_float4(0.f, 0.f, 0.f, 0.f);
    float4 u_nxt = make_float4(0.f, 0.f, 0.f, 0.f);
    if (act && (t + 1 < T_)) {
      const size_t off = ((size_t)(t + 1) * B_ + b) * H_ + h;
      c_nxt = *(const float4*)(C1 + off);
      u_nxt = *(const float4*)(u1 + off);
    }

    // ---- layer-1 LIF + spike-gated W2 accumulation ----
    float part0 = 0.f, part1 = 0.f, part2 = 0.f, part3 = 0.f;
    if (act) {
      const float cs[4] = {c_cur.x, c_cur.y, c_cur.z, c_cur.w};
      const float us[4] = {u_cur.x, u_cur.y, u_cur.z, u_cur.w};
#pragma unroll
      for (int j = 0; j < 4; ++j) {
        float m = fmaf(0.9f, mem1v[j], cs[j]);
        const float z = m - (1.0f + th1v[j]);
        const float p = sigmoid_f(z);
        const float spk = (us[j] < p) ? 1.0f : 0.0f;
        m = (spk != 0.0f) ? 0.0f : m;
        th1v[j] = fmaf(0.9f, th1v[j], 0.05f * spk);
        mem1v[j] = m;
        part0 = fmaf(spk, wreg[0][j], part0);
        part1 = fmaf(spk, wreg[1][j], part1);
        part2 = fmaf(spk, wreg[2][j], part2);
        part3 = fmaf(spk, wreg[3][j], part3);
      }
    }

    // ---- wave-level tree reduce (64 lanes) ----
#pragma unroll
    for (int off = 32; off >= 1; off >>= 1) {
      part0 += __shfl_down(part0, off);
      part1 += __shfl_down(part1, off);
      part2 += __shfl_down(part2, off);
      part3 += __shfl_down(part3, off);
    }
    if (lane == 0) {
      float* r = &sRed[t & 1][wv][0];
      r[0] = part0;
      r[1] = part1;
      r[2] = part2;
      r[3] = part3;
    }
    __syncthreads();

    // ---- layer-2 LIF: 4 lanes, one action each ----
    if (tid < A_) {
      const int a = tid;
      const float cur2 = sRed[t & 1][0][a] + sRed[t & 1][1][a] +
                         sRed[t & 1][2][a] + sRed[t & 1][3][a] + b2v;
      float m = fmaf(0.9f, mem2v, cur2);
      const float z = m - (1.0f + th2v);
      const float p = sigmoid_f(z);
      const float u = sU2[t * A_ + a];
      const float spk = (u < p) ? 1.0f : 0.0f;
      mem2v = (spk != 0.0f) ? 0.0f : m;
      th2v = fmaf(0.9f, th2v, 0.05f * spk);
      scnt += spk;
    }

    c_cur = c_nxt;
    u_cur = u_nxt;
  }

  if (tid < A_) out[b * A_ + tid] = scnt * (1.0f / 64.0f);
}

extern "C" void kernel_launch(void* const* d_in, const int* in_sizes, int n_in,
                              void* d_out, int out_size, void* d_ws,
                              size_t ws_size, hipStream_t stream) {
  const float* x = (const float*)d_in[0];   // [B,T,D]
  const float* W1 = (const float*)d_in[1];  // [H,D]
  const float* b1 = (const float*)d_in[2];  // [H]
  const float* W2 = (const float*)d_in[3];  // [A,H]
  const float* b2 = (const float*)d_in[4];  // [A]
  const float* u1 = (const float*)d_in[5];  // [T,B,H]
  const float* u2 = (const float*)d_in[6];  // [T,B,A]
  float* out = (float*)d_out;               // [B,A]
  float* C1 = (float*)d_ws;                 // [T,B,H] = 65.536 MB scratch

  dim3 g1((H_ + BN - 1) / BN, (B_ * T_) / BM);  // (8, 64)
  gemm1_kernel<<<g1, 256, 0, stream>>>(x, W1, b1, C1);
  snn_seq_kernel<<<B_, 256, 0, stream>>>(C1, u1, W2, b2, u2, out);
}